// Round 1
// baseline (1823.196 us; speedup 1.0000x reference)
//
#include <hip/hip_runtime.h>
#include <math.h>

#define DEV __device__ __forceinline__

DEV float gelu_f(float x) { return 0.5f * x * (1.f + erff(x * 0.70710678118654752f)); }

// ---------------- zero fill ----------------
__global__ void fill_zero(float* __restrict__ p, long n) {
  long i = (long)blockIdx.x * blockDim.x + threadIdx.x;
  long st = (long)gridDim.x * blockDim.x;
  for (; i < n; i += st) p[i] = 0.f;
}

// ---------------- compose We' = attr1_W @ We[l], be' = attr1_b @ We[l], l in [0,6) ----------------
__global__ __launch_bounds__(256) void compose_we(
    const float* __restrict__ a1W, const float* __restrict__ a1b,
    const float* __restrict__ c1We, const float* __restrict__ c2We,
    float* __restrict__ WEC, float* __restrict__ BEC)
{
  int l = blockIdx.x;
  const float* We = (l < 3) ? (c1We + l * 4096) : (c2We + (l - 3) * 4096);
  __shared__ float wes[4096];
  int tid = threadIdx.x;
  for (int i = tid; i < 4096; i += 256) wes[i] = We[i];
  __syncthreads();
  for (int i = tid; i < 1024; i += 256) {
    int k = i >> 6, j = i & 63;
    float s = 0.f;
    #pragma unroll 16
    for (int m = 0; m < 64; ++m) s += a1W[k * 64 + m] * wes[m * 64 + j];
    WEC[l * 1024 + i] = s;
  }
  if (tid < 64) {
    float s = 0.f;
    for (int m = 0; m < 64; ++m) s += a1b[m] * wes[m * 64 + tid];
    BEC[l * 64 + tid] = s;
  }
}

// ---------------- tiled GEMM: O = act(X@W + b), 64 output cols, optional second W ----------------
// block 256 threads; tile 64 rows x 64 cols; per-thread 4x4
template <int ACT, bool PAIR>
__global__ __launch_bounds__(256) void gemm_tile(
    const float* __restrict__ X, int nrows, int K,
    const float* __restrict__ W1, const float* __restrict__ b1, float* __restrict__ O1,
    const float* __restrict__ W2, const float* __restrict__ b2, float* __restrict__ O2)
{
  __shared__ float xs[64][68];
  __shared__ float ws1[64][68];
  __shared__ float ws2[PAIR ? 64 : 1][68];
  const int tid = threadIdx.x;
  const int row0 = blockIdx.x * 64;
  const int tr = tid >> 4;   // 0..15 -> rows tr*4..tr*4+3
  const int tc = tid & 15;   // 0..15 -> cols tc*4..tc*4+3
  float acc1[4][4] = {{0.f,0.f,0.f,0.f},{0.f,0.f,0.f,0.f},{0.f,0.f,0.f,0.f},{0.f,0.f,0.f,0.f}};
  float acc2[4][4] = {{0.f,0.f,0.f,0.f},{0.f,0.f,0.f,0.f},{0.f,0.f,0.f,0.f},{0.f,0.f,0.f,0.f}};

  for (int kc = 0; kc < K; kc += 64) {
    const int klen = min(64, K - kc);
    __syncthreads();
    for (int i = tid; i < 4096; i += 256) {
      int r = i >> 6, c = i & 63;
      int gr = row0 + r;
      float v = 0.f;
      if (gr < nrows && c < klen) v = X[(size_t)gr * K + kc + c];
      xs[r][c] = v;
      float w1v = 0.f, w2v = 0.f;
      if (r < klen) {
        w1v = W1[(size_t)(kc + r) * 64 + c];
        if (PAIR) w2v = W2[(size_t)(kc + r) * 64 + c];
      }
      ws1[r][c] = w1v;
      if (PAIR) ws2[r][c] = w2v;
    }
    __syncthreads();
    #pragma unroll 8
    for (int k = 0; k < 64; ++k) {
      float xv[4];
      #pragma unroll
      for (int i = 0; i < 4; ++i) xv[i] = xs[tr * 4 + i][k];
      float4 w1 = *(const float4*)&ws1[k][tc * 4];
      #pragma unroll
      for (int i = 0; i < 4; ++i) {
        acc1[i][0] += xv[i] * w1.x; acc1[i][1] += xv[i] * w1.y;
        acc1[i][2] += xv[i] * w1.z; acc1[i][3] += xv[i] * w1.w;
      }
      if (PAIR) {
        float4 w2 = *(const float4*)&ws2[k][tc * 4];
        #pragma unroll
        for (int i = 0; i < 4; ++i) {
          acc2[i][0] += xv[i] * w2.x; acc2[i][1] += xv[i] * w2.y;
          acc2[i][2] += xv[i] * w2.z; acc2[i][3] += xv[i] * w2.w;
        }
      }
    }
  }

  float4 bv1 = *(const float4*)&b1[tc * 4];
  float4 bv2 = bv1;
  if (PAIR) bv2 = *(const float4*)&b2[tc * 4];
  #pragma unroll
  for (int i = 0; i < 4; ++i) {
    int gr = row0 + tr * 4 + i;
    if (gr >= nrows) continue;
    float4 o;
    o.x = acc1[i][0] + bv1.x; o.y = acc1[i][1] + bv1.y;
    o.z = acc1[i][2] + bv1.z; o.w = acc1[i][3] + bv1.w;
    if (ACT == 1) { o.x = gelu_f(o.x); o.y = gelu_f(o.y); o.z = gelu_f(o.z); o.w = gelu_f(o.w); }
    *(float4*)&O1[(size_t)gr * 64 + tc * 4] = o;
    if (PAIR) {
      float4 p;
      p.x = acc2[i][0] + bv2.x; p.y = acc2[i][1] + bv2.y;
      p.z = acc2[i][2] + bv2.z; p.w = acc2[i][3] + bv2.w;
      *(float4*)&O2[(size_t)gr * 64 + tc * 4] = p;
    }
  }
}

// ---------------- GATv2 edge pass (node graphs): logit -> exp -> accumulate ----------------
// wave per edge, 4 edges per wave. ep = attr[e] @ WEC + BEC (composed).
__global__ __launch_bounds__(256) void gat_edge(
    const int* __restrict__ esrc, const int* __restrict__ edst, int E,
    const float* __restrict__ attr,
    const float* __restrict__ wec, const float* __restrict__ bec,
    const float* __restrict__ att,
    const float* __restrict__ xl, const float* __restrict__ xr,
    float* __restrict__ num, float* __restrict__ den)
{
  __shared__ float wecs[1024];
  __shared__ float becs[64], atts[64];
  int tid = threadIdx.x;
  for (int i = tid; i < 1024; i += 256) wecs[i] = wec[i];
  if (tid < 64) { becs[tid] = bec[tid]; atts[tid] = att[tid]; }
  __syncthreads();
  int wid = tid >> 6, lane = tid & 63;
  long e0 = ((long)blockIdx.x * 4 + wid) * 4;
  for (int it = 0; it < 4; ++it) {
    long e = e0 + it;
    if (e >= E) return;
    int s = esrc[e], d = edst[e];
    float al = attr[e * 16 + (lane & 15)];
    float ep = becs[lane];
    #pragma unroll
    for (int k = 0; k < 16; ++k)
      ep += __shfl(al, k, 64) * wecs[k * 64 + lane];
    float xlv = xl[(size_t)s * 64 + lane];
    float xrv = xr[(size_t)d * 64 + lane];
    float m = xlv + xrv + ep;
    float lr = m < 0.f ? 0.2f * m : m;
    float t = atts[lane] * lr;
    #pragma unroll
    for (int o = 32; o; o >>= 1) t += __shfl_xor(t, o, 64);
    float ex = expf(t);
    atomicAdd(&num[(size_t)d * 64 + lane], ex * xlv);
    if (lane == 0) atomicAdd(&den[d], ex);
  }
}

// ---------------- GATv2 edge pass (segment graph, edge_dim=1) ----------------
__global__ __launch_bounds__(256) void gat_edge_seg(
    const int* __restrict__ rows, const int* __restrict__ cols,
    const float* __restrict__ vals, int nnz,
    const float* __restrict__ we3, const float* __restrict__ att,
    const float* __restrict__ xl, const float* __restrict__ xr,
    float* __restrict__ num, float* __restrict__ den)
{
  __shared__ float we3s[64], atts[64];
  int tid = threadIdx.x;
  if (tid < 64) { we3s[tid] = we3[tid]; atts[tid] = att[tid]; }
  __syncthreads();
  int wid = tid >> 6, lane = tid & 63;
  long e0 = ((long)blockIdx.x * 4 + wid) * 4;
  for (int it = 0; it < 4; ++it) {
    long e = e0 + it;
    if (e >= nnz) return;
    int s = rows[e], d = cols[e];
    float ep = vals[e] * we3s[lane];
    float xlv = xl[(size_t)s * 64 + lane];
    float xrv = xr[(size_t)d * 64 + lane];
    float m = xlv + xrv + ep;
    float lr = m < 0.f ? 0.2f * m : m;
    float t = atts[lane] * lr;
    #pragma unroll
    for (int o = 32; o; o >>= 1) t += __shfl_xor(t, o, 64);
    float ex = expf(t);
    atomicAdd(&num[(size_t)d * 64 + lane], ex * xlv);
    if (lane == 0) atomicAdd(&den[d], ex);
  }
}

// ---------------- finalize: out = gelu(num/den + bias) [+ pre]; re-zero num/den ----------------
__global__ __launch_bounds__(256) void gat_finalize(
    float* __restrict__ num, float* __restrict__ den,
    const float* __restrict__ bias, const float* __restrict__ pre,
    float* __restrict__ out, int n)
{
  int wid = threadIdx.x >> 6, lane = threadIdx.x & 63;
  int i = blockIdx.x * 4 + wid;
  if (i >= n) return;
  size_t base = (size_t)i * 64;
  float d = den[i] + 1e-16f;
  float v = num[base + lane] / d + bias[lane];
  float g = gelu_f(v);
  out[base + lane] = pre ? (g + pre[base + lane]) : g;
  num[base + lane] = 0.f;
  if (lane == 0) den[i] = 0.f;
}

// ---------------- xf init: [S,448] = [seg_embed | 0 | 0 | 0 | 0 | t | w] ----------------
__global__ void xf_init(
    float* __restrict__ xf, const float* __restrict__ seg_embed,
    const float* __restrict__ time_embed, const float* __restrict__ week_embed,
    const int* __restrict__ cur_t, const int* __restrict__ cur_w, int S)
{
  long idx = (long)blockIdx.x * blockDim.x + threadIdx.x;
  if (idx >= (long)S * 448) return;
  int s = idx / 448, c = idx % 448;
  float v;
  if (c < 64)       v = seg_embed[(size_t)s * 64 + c];
  else if (c < 320) v = 0.f;
  else if (c < 384) v = time_embed[cur_t[0] * 64 + (c - 320)];
  else              v = week_embed[cur_w[0] * 64 + (c - 384)];
  xf[idx] = v;
}

// ---------------- spmm se: x1e (edge_embed) + x2e (attr@W2+b2) into xf cols [64,192) ----------------
__global__ __launch_bounds__(256) void spmm_se(
    const int* __restrict__ srow, const int* __restrict__ scol,
    const float* __restrict__ sval, int nnz,
    const float* __restrict__ edge_embed, const float* __restrict__ attr,
    const float* __restrict__ W2, const float* __restrict__ b2,
    float* __restrict__ xf)
{
  __shared__ float ws[1024];
  __shared__ float bs[64];
  int tid = threadIdx.x;
  for (int i = tid; i < 1024; i += 256) ws[i] = W2[i];
  if (tid < 64) bs[tid] = b2[tid];
  __syncthreads();
  int wid = tid >> 6, lane = tid & 63;
  long i0 = ((long)blockIdx.x * 4 + wid) * 4;
  for (int it = 0; it < 4; ++it) {
    long i = i0 + it;
    if (i >= nnz) return;
    int r = srow[i], c = scol[i];
    float v = sval[i];
    float e1 = edge_embed[(size_t)c * 64 + lane];
    atomicAdd(&xf[(size_t)r * 448 + 64 + lane], v * e1);
    float al = attr[(size_t)c * 16 + (lane & 15)];
    float m2 = bs[lane];
    #pragma unroll
    for (int k = 0; k < 16; ++k)
      m2 += __shfl(al, k, 64) * ws[k * 64 + lane];
    atomicAdd(&xf[(size_t)r * 448 + 128 + lane], v * m2);
  }
}

// ---------------- spmm sn: x1n (h) + x2n (nf) into xf cols [192,320) ----------------
__global__ __launch_bounds__(256) void spmm_sn(
    const int* __restrict__ srow, const int* __restrict__ scol,
    const float* __restrict__ sval, int nnz,
    const float* __restrict__ h, const float* __restrict__ nf,
    float* __restrict__ xf)
{
  int tid = threadIdx.x;
  int wid = tid >> 6, lane = tid & 63;
  long i0 = ((long)blockIdx.x * 4 + wid) * 4;
  for (int it = 0; it < 4; ++it) {
    long i = i0 + it;
    if (i >= nnz) return;
    int r = srow[i], c = scol[i];
    float v = sval[i];
    atomicAdd(&xf[(size_t)r * 448 + 192 + lane], v * h[(size_t)c * 64 + lane]);
    atomicAdd(&xf[(size_t)r * 448 + 256 + lane], v * nf[(size_t)c * 64 + lane]);
  }
}

// ---------------- head: out = sigmoid([y2|xfg]@outW + b)*3600 ----------------
__global__ __launch_bounds__(256) void head_k(
    const float* __restrict__ y2, const float* __restrict__ xfg,
    const float* __restrict__ outW, const float* __restrict__ outb,
    float* __restrict__ out, int S)
{
  int wid = threadIdx.x >> 6, lane = threadIdx.x & 63;
  int s = blockIdx.x * 4 + wid;
  if (s >= S) return;
  float t = y2[(size_t)s * 64 + lane] * outW[lane] + xfg[(size_t)s * 64 + lane] * outW[64 + lane];
  #pragma unroll
  for (int o = 32; o; o >>= 1) t += __shfl_xor(t, o, 64);
  if (lane == 0) {
    float z = t + outb[0];
    out[s] = 3600.f / (1.f + expf(-z));
  }
}

extern "C" void kernel_launch(void* const* d_in, const int* in_sizes, int n_in,
                              void* d_out, int out_size, void* d_ws, size_t ws_size,
                              hipStream_t stream)
{
  const float* x_rec       = (const float*)d_in[0];
  const float* attr        = (const float*)d_in[1];
  const float* se_val      = (const float*)d_in[2];
  const float* sn_val      = (const float*)d_in[3];
  const float* ss_val      = (const float*)d_in[4];
  const float* node_embed  = (const float*)d_in[5];
  const float* edge_embed  = (const float*)d_in[6];
  const float* seg_embed   = (const float*)d_in[7];
  const float* time_embed  = (const float*)d_in[8];
  const float* week_embed  = (const float*)d_in[9];
  const float* node_lin_W  = (const float*)d_in[10];
  const float* node_lin_b  = (const float*)d_in[11];
  const float* attr1_W     = (const float*)d_in[12];
  const float* attr1_b     = (const float*)d_in[13];
  const float* attr2_W     = (const float*)d_in[14];
  const float* attr2_b     = (const float*)d_in[15];
  const float* c1_Wl       = (const float*)d_in[16];
  const float* c1_bl       = (const float*)d_in[17];
  const float* c1_Wr       = (const float*)d_in[18];
  const float* c1_br       = (const float*)d_in[19];
  // c1_We = d_in[20] (used via compose)
  const float* c1_att      = (const float*)d_in[21];
  const float* c1_bias     = (const float*)d_in[22];
  const float* c2_Wl       = (const float*)d_in[23];
  const float* c2_bl       = (const float*)d_in[24];
  const float* c2_Wr       = (const float*)d_in[25];
  const float* c2_br       = (const float*)d_in[26];
  // c2_We = d_in[27]
  const float* c2_att      = (const float*)d_in[28];
  const float* c2_bias     = (const float*)d_in[29];
  const float* c3_Wl       = (const float*)d_in[30];
  const float* c3_bl       = (const float*)d_in[31];
  const float* c3_Wr       = (const float*)d_in[32];
  const float* c3_br       = (const float*)d_in[33];
  const float* c3_We       = (const float*)d_in[34];
  const float* c3_att      = (const float*)d_in[35];
  const float* c3_bias     = (const float*)d_in[36];
  const float* lin1_W      = (const float*)d_in[37];
  const float* lin1_b      = (const float*)d_in[38];
  const float* lin2_W      = (const float*)d_in[39];
  const float* lin2_b      = (const float*)d_in[40];
  const float* out_W       = (const float*)d_in[41];
  const float* out_b       = (const float*)d_in[42];
  const int* edge_index    = (const int*)d_in[43];
  const int* se_row        = (const int*)d_in[44];
  const int* se_col        = (const int*)d_in[45];
  const int* sn_row        = (const int*)d_in[46];
  const int* sn_col        = (const int*)d_in[47];
  const int* ss_row        = (const int*)d_in[48];
  const int* ss_col        = (const int*)d_in[49];
  const int* cur_t         = (const int*)d_in[50];
  const int* cur_w         = (const int*)d_in[51];

  const int N = in_sizes[0] / 32;
  const int E = in_sizes[1] / 16;
  const int S = in_sizes[7] / 64;
  const int NNZSS = in_sizes[4];

  // workspace layout (floats)
  float* W = (float*)d_ws;
  size_t o = 0;
  float* A   = W + o; o += (size_t)N * 64;  // xl / xl3 / xfgnn / y2
  float* B   = W + o; o += (size_t)N * 64;  // xr / xr3 / y
  float* C   = W + o; o += (size_t)N * 64;  // num (zeroed between uses)
  float* D   = W + o; o += (size_t)N;       // den (zeroed between uses)
  float* Hc  = W + o; o += (size_t)N * 64;  // conv1 state / final h
  float* F0  = W + o; o += (size_t)N * 64;  // nf0 (conv2 pre)
  float* Fc  = W + o; o += (size_t)N * 64;  // conv2 state / final nf
  float* XF  = W + o; o += (size_t)S * 448; // xf [S,448]
  float* WEC = W + o; o += 6 * 1024;        // composed We (6 layers)
  float* BEC = W + o; o += 6 * 64;          // composed be
  float* XFG = A;                           // xf_gnn (xl3 dead by then)
  float* Y   = B;                           // y     (xr3 dead by then)
  float* Y2  = A + (size_t)S * 64;          // after xfgnn region

  dim3 blk(256);
  const int gN64  = (N + 63) / 64;
  const int gS64  = (S + 63) / 64;
  const int gE16  = (E + 15) / 16;
  const int gN4   = (N + 3) / 4;
  const int gS4   = (S + 3) / 4;
  const int gZ16  = (NNZSS + 15) / 16;

  // composed edge-projection weights; zero num/den (C and D are contiguous)
  compose_we<<<6, blk, 0, stream>>>(attr1_W, attr1_b,
                                    (const float*)d_in[20], (const float*)d_in[27], WEC, BEC);
  fill_zero<<<2048, blk, 0, stream>>>(C, (long)N * 64 + N);

  // nf0 = gelu(x_rec @ node_lin_W + b)   (K=32)
  gemm_tile<1, false><<<gN64, blk, 0, stream>>>(x_rec, N, 32, node_lin_W, node_lin_b, F0,
                                                nullptr, nullptr, nullptr);

  // conv1 stack (pre = node_embed)
  const float* state = node_embed;
  for (int l = 0; l < 3; ++l) {
    gemm_tile<0, true><<<gN64, blk, 0, stream>>>(state, N, 64,
        c1_Wl + l * 4096, c1_bl + l * 64, A, c1_Wr + l * 4096, c1_br + l * 64, B);
    gat_edge<<<gE16, blk, 0, stream>>>(edge_index, edge_index + E, E, attr,
        WEC + l * 1024, BEC + l * 64, c1_att + l * 64, A, B, C, D);
    gat_finalize<<<gN4, blk, 0, stream>>>(C, D, c1_bias + l * 64, node_embed, Hc, N);
    state = Hc;
  }

  // conv2 stack (pre = F0)
  state = F0;
  for (int l = 0; l < 3; ++l) {
    gemm_tile<0, true><<<gN64, blk, 0, stream>>>(state, N, 64,
        c2_Wl + l * 4096, c2_bl + l * 64, A, c2_Wr + l * 4096, c2_br + l * 64, B);
    gat_edge<<<gE16, blk, 0, stream>>>(edge_index, edge_index + E, E, attr,
        WEC + (3 + l) * 1024, BEC + (3 + l) * 64, c2_att + l * 64, A, B, C, D);
    gat_finalize<<<gN4, blk, 0, stream>>>(C, D, c2_bias + l * 64, F0, Fc, N);
    state = Fc;
  }

  // xf assembly
  xf_init<<<((long)S * 448 + 255) / 256, blk, 0, stream>>>(XF, seg_embed, time_embed, week_embed,
                                                           cur_t, cur_w, S);
  spmm_se<<<gE16, blk, 0, stream>>>(se_row, se_col, se_val, E, edge_embed, attr,
                                    attr2_W, attr2_b, XF);
  spmm_sn<<<gE16, blk, 0, stream>>>(sn_row, sn_col, sn_val, E, Hc, Fc, XF);

  // conv3 on segment graph (K=448)
  gemm_tile<0, true><<<gS64, blk, 0, stream>>>(XF, S, 448, c3_Wl, c3_bl, A, c3_Wr, c3_br, B);
  gat_edge_seg<<<gZ16, blk, 0, stream>>>(ss_row, ss_col, ss_val, NNZSS, c3_We, c3_att, A, B, C, D);
  gat_finalize<<<gS4, blk, 0, stream>>>(C, D, c3_bias, nullptr, XFG, S);

  // MLP head
  gemm_tile<1, false><<<gS64, blk, 0, stream>>>(XF, S, 448, lin1_W, lin1_b, Y,
                                                nullptr, nullptr, nullptr);
  gemm_tile<1, false><<<gS64, blk, 0, stream>>>(Y, S, 64, lin2_W, lin2_b, Y2,
                                                nullptr, nullptr, nullptr);
  head_k<<<gS4, blk, 0, stream>>>(Y2, XFG, out_W, out_b, (float*)d_out, S);
}